// Round 8
// baseline (676.320 us; speedup 1.0000x reference)
//
#include <hip/hip_runtime.h>
#include <hip/hip_bf16.h>

// Problem constants
#define NB 8
#define NH 8
#define LQ 1024
#define LK 1024
#define DD 64
#define EC 0.18033688011112042f      // (1/8) * log2(e)
#define OUT0_SIZE (8ull*8*1024*64)   // output [B,H,LQ,D]

typedef __bf16 bf16x8 __attribute__((ext_vector_type(8)));
typedef __bf16 bf16x4 __attribute__((ext_vector_type(4)));
typedef float  f32x4  __attribute__((ext_vector_type(4)));

static __device__ __forceinline__ __bf16 f2b(float f) {
    unsigned u = __builtin_bit_cast(unsigned, f);
    unsigned r = (u + 0x7fffu + ((u >> 16) & 1u)) >> 16;
    return __builtin_bit_cast(__bf16, (unsigned short)r);
}

// ---------------------------------------------------------------------------
// K0a: independent 64x64x64 f32 products
// ---------------------------------------------------------------------------
__global__ __launch_bounds__(256) void fold_pairs(
        const float* __restrict__ pWA, const float* __restrict__ pWB,
        const float* __restrict__ pWBt, const float* __restrict__ pWAt,
        const float* __restrict__ pWav, const float* __restrict__ pWbv,
        float* __restrict__ P1, float* __restrict__ P2, float* __restrict__ Wv) {
    __shared__ float AT[64*68];
    __shared__ float Bl[64*64];
    const int h = blockIdx.x / 3;
    const int which = blockIdx.x - h*3;
    const int t = threadIdx.x;
    const float *A, *B; float* C;
    if (which == 0)      { A = pWA  + h*4096; B = pWB  + h*4096; C = P1 + h*4096; }
    else if (which == 1) { A = pWBt + h*4096; B = pWAt + h*4096; C = P2 + h*4096; }
    else                 { A = pWav + h*4096; B = pWbv + h*4096; C = Wv + h*4096; }

    for (int i = t; i < 4096; i += 256) {
        int r = i >> 6, c = i & 63;
        AT[c*68 + r] = A[i];
        Bl[i] = B[i];
    }
    __syncthreads();
    const int r0 = (t >> 4) * 4, j0 = (t & 15) * 4;
    float acc[4][4] = {};
    #pragma unroll 8
    for (int k = 0; k < 64; ++k) {
        f32x4 a = *(const f32x4*)&AT[k*68 + r0];
        f32x4 b = *(const f32x4*)&Bl[k*64 + j0];
        #pragma unroll
        for (int i = 0; i < 4; ++i)
            #pragma unroll
            for (int j = 0; j < 4; ++j) acc[i][j] += a[i] * b[j];
    }
    #pragma unroll
    for (int i = 0; i < 4; ++i) {
        f32x4 o = { acc[i][0], acc[i][1], acc[i][2], acc[i][3] };
        *(f32x4*)&C[(r0 + i)*64 + j0] = o;
    }
}

// K0b: W = P1 @ P2
__global__ __launch_bounds__(256) void fold_final(
        const float* __restrict__ P1, const float* __restrict__ P2,
        float* __restrict__ Wout) {
    __shared__ float AT[64*68];
    __shared__ float Bl[64*64];
    const int h = blockIdx.x;
    const int t = threadIdx.x;
    for (int i = t; i < 4096; i += 256) {
        int r = i >> 6, c = i & 63;
        AT[c*68 + r] = P1[h*4096 + i];
        Bl[i] = P2[h*4096 + i];
    }
    __syncthreads();
    const int r0 = (t >> 4) * 4, j0 = (t & 15) * 4;
    float acc[4][4] = {};
    #pragma unroll 8
    for (int k = 0; k < 64; ++k) {
        f32x4 a = *(const f32x4*)&AT[k*68 + r0];
        f32x4 b = *(const f32x4*)&Bl[k*64 + j0];
        #pragma unroll
        for (int i = 0; i < 4; ++i)
            #pragma unroll
            for (int j = 0; j < 4; ++j) acc[i][j] += a[i] * b[j];
    }
    #pragma unroll
    for (int i = 0; i < 4; ++i) {
        f32x4 o = { acc[i][0], acc[i][1], acc[i][2], acc[i][3] };
        *(f32x4*)&Wout[h*4096 + (r0 + i)*64 + j0] = o;
    }
}

// ---------------------------------------------------------------------------
// K1 (merged prepass)
// ---------------------------------------------------------------------------
__global__ __launch_bounds__(256) void prepass(
        const float* __restrict__ q, const float* __restrict__ W,
        const float* __restrict__ qt, const float* __restrict__ v,
        const float* __restrict__ Wv,
        __bf16* __restrict__ qW, __bf16* __restrict__ qtT,
        __bf16* __restrict__ vWT) {
    __shared__ float smem[8448];
    const int bh = blockIdx.x;
    const int by = blockIdx.y;
    const int batch = bh >> 3, h = bh & 7;
    const int t = threadIdx.x;

    if (by < 16) {
        float* qT = smem;            // [c][r] 64x68
        float* Wl = smem + 4352;     // [c][j] 64x64
        const int a0 = by * 64;
        for (int i = t; i < 4096; i += 256) {
            int r = i >> 6, c = i & 63;
            Wl[i] = W[h*4096 + i];
            qT[c*68 + r] = q[(((size_t)batch*LQ + a0 + r)*NH + h)*DD + c];
        }
        __syncthreads();
        const int r0 = (t >> 4) * 4, j0 = (t & 15) * 4;
        float acc[4][4] = {};
        #pragma unroll 8
        for (int c = 0; c < 64; ++c) {
            f32x4 a = *(const f32x4*)&qT[c*68 + r0];
            f32x4 b = *(const f32x4*)&Wl[c*64 + j0];
            #pragma unroll
            for (int i = 0; i < 4; ++i)
                #pragma unroll
                for (int j = 0; j < 4; ++j) acc[i][j] += a[i] * b[j];
        }
        #pragma unroll
        for (int i = 0; i < 4; ++i) {
            bf16x4 o;
            #pragma unroll
            for (int j = 0; j < 4; ++j) o[j] = f2b(acc[i][j]);
            *(bf16x4*)&qW[((size_t)bh*LQ + a0 + r0 + i)*DD + j0] = o;
        }
    } else if (by < 24) {
        float* tile = smem;          // [j][n] 64x132
        const int n0 = (by - 16) * 128;
        #pragma unroll
        for (int it = 0; it < 8; ++it) {
            int idx = (t + 256*it) * 4;
            int j = idx >> 7, n = idx & 127;
            *(f32x4*)&tile[j*132 + n] = *(const f32x4*)&qt[((size_t)bh*DD + j)*LK + n0 + n];
        }
        __syncthreads();
        const int j0 = (t & 15) * 4;
        #pragma unroll
        for (int it = 0; it < 8; ++it) {
            int n = (t >> 4) + 16*it;
            bf16x4 o;
            #pragma unroll
            for (int i = 0; i < 4; ++i) o[i] = f2b(tile[(j0 + i)*132 + n]);
            *(bf16x4*)&qtT[((size_t)bh*LK + n0 + n)*DD + j0] = o;
        }
    } else {
        float* vT  = smem;           // [n][m] 64x68
        float* Wvl = smem + 4352;    // [n][c] 64x64
        const int mb0 = (by - 24) * 64;
        for (int i = t; i < 4096; i += 256) {
            int r = i >> 6, c = i & 63;     // r = m-row, c = n
            Wvl[i] = Wv[h*4096 + i];
            vT[c*68 + r] = v[(((size_t)batch*LK + mb0 + r)*NH + h)*DD + c];
        }
        __syncthreads();
        const int c0 = (t >> 4) * 4, m0 = (t & 15) * 4;
        float acc[4][4] = {};               // [c][m]
        #pragma unroll 8
        for (int n = 0; n < 64; ++n) {
            f32x4 wv = *(const f32x4*)&Wvl[n*64 + c0];
            f32x4 vv = *(const f32x4*)&vT[n*68 + m0];
            #pragma unroll
            for (int ci = 0; ci < 4; ++ci)
                #pragma unroll
                for (int mi = 0; mi < 4; ++mi) acc[ci][mi] += wv[ci] * vv[mi];
        }
        #pragma unroll
        for (int ci = 0; ci < 4; ++ci) {
            bf16x4 o;
            #pragma unroll
            for (int mi = 0; mi < 4; ++mi) o[mi] = f2b(acc[ci][mi]);
            *(bf16x4*)&vWT[((size_t)bh*DD + c0 + ci)*LK + mb0 + m0] = o;
        }
    }
}

// ---------------------------------------------------------------------------
// PROBE A x2: exact R5 store schedule run twice (rep1 targets bh^63 to avoid
// same-line replay artifacts). dur ~= 2 * T_store. Garbage output; fully
// overwritten by the real attn kernel afterwards.
// ---------------------------------------------------------------------------
__global__ __launch_bounds__(256) void store_probe2(float* __restrict__ out) {
    __shared__ __align__(16) char smemraw[35584];
    float* Pt   = (float*)(smemraw + 9216);
    float* Obuf = (float*)(smemraw + 9216 + 17408);

    const int bid = blockIdx.x;
    const int xcd = bid & 7, s = bid >> 3;
    const int bh0 = xcd * 8 + (s >> 5);
    const int a0  = (s & 31) * 32;
    const int t   = threadIdx.x;
    const int w   = t >> 6, l = t & 63;
    const int strip = w & 1, nh = w >> 1;
    const int qbase = a0 + strip * 16;
    const int n0w   = nh * 512;

    for (int i = t; i < 35584/4; i += 256) ((float*)smemraw)[i] = (float)(i & 63) * 0.015625f;
    __syncthreads();

    const int rr = l >> 4, cc = l & 15;
    for (int rep = 0; rep < 2; ++rep) {
        const int bh = bh0 ^ (rep ? 63 : 0);
        float* attnb = out + OUT0_SIZE + ((size_t)bh << 20);
        #pragma unroll
        for (int nc = 0; nc < 8; ++nc) {
            const int nbase = n0w + nc*64;
            #pragma unroll
            for (int it = 0; it < 4; ++it) {
                int row = it*4 + rr;
                f32x4 p = *(const f32x4*)&Pt[(w*16 + row)*68 + cc*4];
                __builtin_nontemporal_store(p,
                    (f32x4*)&attnb[((size_t)(qbase + row) << 10) + nbase + cc*4]);
            }
        }
        #pragma unroll
        for (int it = 0; it < 2; ++it) {
            int row = it*16 + w*4 + rr;
            f32x4 o = *(const f32x4*)&Obuf[row*68 + cc*4];
            __builtin_nontemporal_store(o,
                (f32x4*)&out[(((size_t)bh*LQ + a0 + row) << 6) + cc*4]);
        }
    }
}

// ---------------------------------------------------------------------------
// PROBE B x2: exact R5 compute/load path (global stores -> asm sinks),
// run twice. dur ~= 2 * T_compute.
// ---------------------------------------------------------------------------
__global__ __launch_bounds__(256) void comp_probe2(
        const __bf16* __restrict__ qW, const __bf16* __restrict__ qtT,
        const __bf16* __restrict__ vWT, float* __restrict__ out) {
    __shared__ __align__(16) __bf16 Elds[4][16][72];
    __shared__ __align__(16) float  Pt[4][16][68];
    __shared__ __align__(16) float  Obuf[32][68];
    __shared__ float rsumbuf[2][2][16];

    const int bid = blockIdx.x;
    const int xcd = bid & 7, s = bid >> 3;
    const int bh  = xcd * 8 + (s >> 5);
    const int a0  = (s & 31) * 32;
    const int t   = threadIdx.x;
    const int w   = t >> 6, l = t & 63;
    const int lg  = l & 15, g = l >> 4;
    const int strip = w & 1, nh = w >> 1;
    const int qbase = a0 + strip * 16;
    const int n0w   = nh * 512;

    const __bf16* qtb = qtT + (size_t)bh * LK * DD;
    const __bf16* vwb = vWT + (size_t)bh * DD * LK;

    const bf16x8* qWp = reinterpret_cast<const bf16x8*>(qW + ((size_t)bh*LQ + qbase + lg)*DD);
    bf16x8 bfrag0 = qWp[g];
    bf16x8 bfrag1 = qWp[g + 4];
    const int rr = l >> 4, cc = l & 15;

    for (int rep = 0; rep < 2; ++rep) {
        __syncthreads();
        // ---- pass 1 ----
        bf16x8 ka[4][2];
        #pragma unroll
        for (int sub = 0; sub < 4; ++sub) {
            const bf16x8* qtp = (const bf16x8*)(qtb + (size_t)(n0w + sub*16 + lg)*DD);
            ka[sub][0] = qtp[g]; ka[sub][1] = qtp[g + 4];
        }
        float rsum = 0.f;
        #pragma unroll
        for (int nc = 0; nc < 8; ++nc) {
            f32x4 accs[4];
            #pragma unroll
            for (int sub = 0; sub < 4; ++sub) {
                f32x4 acc = {0.f, 0.f, 0.f, 0.f};
                acc = __builtin_amdgcn_mfma_f32_16x16x32_bf16(ka[sub][0], bfrag0, acc, 0, 0, 0);
                acc = __builtin_amdgcn_mfma_f32_16x16x32_bf16(ka[sub][1], bfrag1, acc, 0, 0, 0);
                accs[sub] = acc;
            }
            if (nc < 7) {
                #pragma unroll
                for (int sub = 0; sub < 4; ++sub) {
                    const bf16x8* qtp = (const bf16x8*)(qtb + (size_t)(n0w + (nc+1)*64 + sub*16 + lg)*DD);
                    ka[sub][0] = qtp[g]; ka[sub][1] = qtp[g + 4];
                }
            }
            #pragma unroll
            for (int sub = 0; sub < 4; ++sub)
                #pragma unroll
                for (int r = 0; r < 4; ++r) rsum += __builtin_exp2f(accs[sub][r] * EC);
        }
        rsum += __shfl_xor(rsum, 16);
        rsum += __shfl_xor(rsum, 32);
        if (l < 16) rsumbuf[nh][strip][l] = rsum;
        __syncthreads();
        const float rinv = 1.0f / (rsumbuf[0][strip][lg] + rsumbuf[1][strip][lg]);

        // ---- pass 2 ----
        #pragma unroll
        for (int sub = 0; sub < 4; ++sub) {
            const bf16x8* qtp = (const bf16x8*)(qtb + (size_t)(n0w + sub*16 + lg)*DD);
            ka[sub][0] = qtp[g]; ka[sub][1] = qtp[g + 4];
        }
        bf16x8 vp0[4], vp1[4];
        #pragma unroll
        for (int ct = 0; ct < 4; ++ct) {
            const bf16x8* vpp = (const bf16x8*)(vwb + (size_t)(ct*16 + lg)*LK + n0w);
            vp0[ct] = vpp[g]; vp1[ct] = vpp[4 + g];
        }
        f32x4 oacc[4];
        #pragma unroll
        for (int ct = 0; ct < 4; ++ct) oacc[ct] = f32x4{0.f, 0.f, 0.f, 0.f};

        #pragma unroll
        for (int nc = 0; nc < 8; ++nc) {
            const int nbase = n0w + nc*64;
            #pragma unroll
            for (int sub = 0; sub < 4; ++sub) {
                f32x4 acc = {0.f, 0.f, 0.f, 0.f};
                acc = __builtin_amdgcn_mfma_f32_16x16x32_bf16(ka[sub][0], bfrag0, acc, 0, 0, 0);
                acc = __builtin_amdgcn_mfma_f32_16x16x32_bf16(ka[sub][1], bfrag1, acc, 0, 0, 0);
                f32x4 p; bf16x4 pb;
                #pragma unroll
                for (int r = 0; r < 4; ++r) {
                    float pv_ = __builtin_exp2f(acc[r] * EC) * rinv;
                    p[r] = pv_;
                    pb[r] = f2b(pv_);
                }
                *(f32x4*)&Pt[w][lg][sub*16 + g*4] = p;
                *(bf16x4*)&Elds[w][lg][sub*16 + g*4] = pb;
            }
            if (nc < 7) {
                #pragma unroll
                for (int sub = 0; sub < 4; ++sub) {
                    const bf16x8* qtp = (const bf16x8*)(qtb + (size_t)(nbase + 64 + sub*16 + lg)*DD);
                    ka[sub][0] = qtp[g]; ka[sub][1] = qtp[g + 4];
                }
            }
            bf16x8 pf0 = ((const bf16x8*)&Elds[w][lg][0])[g];
            bf16x8 pf1 = ((const bf16x8*)&Elds[w][lg][0])[4 + g];
            #pragma unroll
            for (int ct = 0; ct < 4; ++ct) {
                oacc[ct] = __builtin_amdgcn_mfma_f32_16x16x32_bf16(vp0[ct], pf0, oacc[ct], 0, 0, 0);
                oacc[ct] = __builtin_amdgcn_mfma_f32_16x16x32_bf16(vp1[ct], pf1, oacc[ct], 0, 0, 0);
            }
            if (nc < 7) {
                #pragma unroll
                for (int ct = 0; ct < 4; ++ct) {
                    const bf16x8* vpp = (const bf16x8*)(vwb + (size_t)(ct*16 + lg)*LK + nbase + 64);
                    vp0[ct] = vpp[g]; vp1[ct] = vpp[4 + g];
                }
            }
            // sink the staged store values (keeps Pt reads + all upstream live)
            #pragma unroll
            for (int it = 0; it < 4; ++it) {
                int row = it*4 + rr;
                f32x4 p = *(const f32x4*)&Pt[w][row][cc*4];
                asm volatile("" :: "v"(p[0]), "v"(p[1]), "v"(p[2]), "v"(p[3]));
            }
        }

        if (nh == 1) {
            #pragma unroll
            for (int ct = 0; ct < 4; ++ct)
                *(f32x4*)&Obuf[strip*16 + lg][ct*16 + g*4] = oacc[ct];
        }
        __syncthreads();
        if (nh == 0) {
            #pragma unroll
            for (int ct = 0; ct < 4; ++ct) {
                f32x4 o = *(const f32x4*)&Obuf[strip*16 + lg][ct*16 + g*4];
                o = o + oacc[ct];
                *(f32x4*)&Obuf[strip*16 + lg][ct*16 + g*4] = o;
            }
        }
        __syncthreads();
        #pragma unroll
        for (int it = 0; it < 2; ++it) {
            int row = it*16 + w*4 + rr;
            f32x4 o = *(const f32x4*)&Obuf[row][cc*4];
            asm volatile("" :: "v"(o[0]), "v"(o[1]), "v"(o[2]), "v"(o[3]));
        }
    }
}

// ---------------------------------------------------------------------------
// K4: real fused kernel (R5 structure, verbatim).
// ---------------------------------------------------------------------------
__global__ __launch_bounds__(256) void attn_kernel(
        const __bf16* __restrict__ qW, const __bf16* __restrict__ qtT,
        const __bf16* __restrict__ vWT, float* __restrict__ out) {
    __shared__ __align__(16) __bf16 Elds[4][16][72];
    __shared__ __align__(16) float  Pt[4][16][68];
    __shared__ __align__(16) float  Obuf[32][68];
    __shared__ float rsumbuf[2][2][16];

    const int bid = blockIdx.x;
    const int xcd = bid & 7, s = bid >> 3;
    const int bh  = xcd * 8 + (s >> 5);
    const int a0  = (s & 31) * 32;
    const int t   = threadIdx.x;
    const int w   = t >> 6, l = t & 63;
    const int lg  = l & 15, g = l >> 4;
    const int strip = w & 1, nh = w >> 1;
    const int qbase = a0 + strip * 16;
    const int n0w   = nh * 512;

    const __bf16* qtb = qtT + (size_t)bh * LK * DD;
    const __bf16* vwb = vWT + (size_t)bh * DD * LK;

    const bf16x8* qWp = reinterpret_cast<const bf16x8*>(qW + ((size_t)bh*LQ + qbase + lg)*DD);
    bf16x8 bfrag0 = qWp[g];
    bf16x8 bfrag1 = qWp[g + 4];

    // ---- pass 1 ----
    bf16x8 ka[4][2];
    #pragma unroll
    for (int sub = 0; sub < 4; ++sub) {
        const bf16x8* qtp = (const bf16x8*)(qtb + (size_t)(n0w + sub*16 + lg)*DD);
        ka[sub][0] = qtp[g]; ka[sub][1] = qtp[g + 4];
    }
    float rsum = 0.f;
    #pragma unroll
    for (int nc = 0; nc < 8; ++nc) {
        f32x4 accs[4];
        #pragma unroll
        for (int sub = 0; sub < 4; ++sub) {
            f32x4 acc = {0.f, 0.f, 0.f, 0.f};
            acc = __builtin_amdgcn_mfma_f32_16x16x32_bf16(ka[sub][0], bfrag0, acc, 0, 0, 0);
            acc = __builtin_amdgcn_mfma_f32_16x16x32_bf16(ka[sub][1], bfrag1, acc, 0, 0, 0);
            accs[sub] = acc;
        }
        if (nc < 7) {
            #pragma unroll
            for (int sub = 0; sub < 4; ++sub) {
                const bf16x8* qtp = (const bf16x8*)(qtb + (size_t)(n0w + (nc+1)*64 + sub*16 + lg)*DD);
                ka[sub][0] = qtp[g]; ka[sub][1] = qtp[g + 4];
            }
        }
        #pragma unroll
        for (int sub = 0; sub < 4; ++sub)
            #pragma unroll
            for (int r = 0; r < 4; ++r) rsum += __builtin_exp2f(accs[sub][r] * EC);
    }
    rsum += __shfl_xor(rsum, 16);
    rsum += __shfl_xor(rsum, 32);
    if (l < 16) rsumbuf[nh][strip][l] = rsum;
    __syncthreads();
    const float rinv = 1.0f / (rsumbuf[0][strip][lg] + rsumbuf[1][strip][lg]);

    // ---- pass 2 ----
    #pragma unroll
    for (int sub = 0; sub < 4; ++sub) {
        const bf16x8* qtp = (const bf16x8*)(qtb + (size_t)(n0w + sub*16 + lg)*DD);
        ka[sub][0] = qtp[g]; ka[sub][1] = qtp[g + 4];
    }
    bf16x8 vp0[4], vp1[4];
    #pragma unroll
    for (int ct = 0; ct < 4; ++ct) {
        const bf16x8* vpp = (const bf16x8*)(vwb + (size_t)(ct*16 + lg)*LK + n0w);
        vp0[ct] = vpp[g]; vp1[ct] = vpp[4 + g];
    }

    f32x4 oacc[4];
    #pragma unroll
    for (int ct = 0; ct < 4; ++ct) oacc[ct] = f32x4{0.f, 0.f, 0.f, 0.f};

    float* attnb = out + OUT0_SIZE + ((size_t)bh << 20);
    const int rr = l >> 4, cc = l & 15;

    #pragma unroll
    for (int nc = 0; nc < 8; ++nc) {
        const int nbase = n0w + nc*64;
        #pragma unroll
        for (int sub = 0; sub < 4; ++sub) {
            f32x4 acc = {0.f, 0.f, 0.f, 0.f};
            acc = __builtin_amdgcn_mfma_f32_16x16x32_bf16(ka[sub][0], bfrag0, acc, 0, 0, 0);
            acc = __builtin_amdgcn_mfma_f32_16x16x32_bf16(ka[sub][1], bfrag1, acc, 0, 0, 0);
            f32x4 p; bf16x4 pb;
            #pragma unroll
            for (int r = 0; r < 4; ++r) {
                float pv_ = __builtin_exp2f(acc[r] * EC) * rinv;
                p[r] = pv_;
                pb[r] = f2b(pv_);
            }
            *(f32x4*)&Pt[w][lg][sub*16 + g*4] = p;
            *(bf16x4*)&Elds[w][lg][sub*16 + g*4] = pb;
        }
        if (nc < 7) {
            #pragma unroll
            for (int sub = 0; sub < 4; ++sub) {
                const bf16x8* qtp = (const bf16x8*)(qtb + (size_t)(nbase + 64 + sub*16 + lg)*DD);
                ka[sub][0] = qtp[g]; ka[sub][1] = qtp[g + 4];
            }
        }
        bf16x8 pf0 = ((const bf16x8*)&Elds[w][lg][0])[g];
        bf16x8 pf1 = ((const bf16x8*)&Elds[w][lg][0])[4 + g];
        #pragma unroll
        for (int ct = 0; ct < 4; ++ct) {
            oacc[ct] = __builtin_amdgcn_mfma_f32_16x16x32_bf16(vp0[ct], pf0, oacc[ct], 0, 0, 0);
            oacc[ct] = __builtin_amdgcn_mfma_f32_16x16x32_bf16(vp1[ct], pf1, oacc[ct], 0, 0, 0);
        }
        if (nc < 7) {
            #pragma unroll
            for (int ct = 0; ct < 4; ++ct) {
                const bf16x8* vpp = (const bf16x8*)(vwb + (size_t)(ct*16 + lg)*LK + nbase + 64);
                vp0[ct] = vpp[g]; vp1[ct] = vpp[4 + g];
            }
        }
        #pragma unroll
        for (int it = 0; it < 4; ++it) {
            int row = it*4 + rr;
            f32x4 p = *(const f32x4*)&Pt[w][row][cc*4];
            __builtin_nontemporal_store(p,
                (f32x4*)&attnb[((size_t)(qbase + row) << 10) + nbase + cc*4]);
        }
    }

    if (nh == 1) {
        #pragma unroll
        for (int ct = 0; ct < 4; ++ct)
            *(f32x4*)&Obuf[strip*16 + lg][ct*16 + g*4] = oacc[ct];
    }
    __syncthreads();
    if (nh == 0) {
        #pragma unroll
        for (int ct = 0; ct < 4; ++ct) {
            f32x4 o = *(const f32x4*)&Obuf[strip*16 + lg][ct*16 + g*4];
            o = o + oacc[ct];
            *(f32x4*)&Obuf[strip*16 + lg][ct*16 + g*4] = o;
        }
    }
    __syncthreads();
    #pragma unroll
    for (int it = 0; it < 2; ++it) {
        int row = it*16 + w*4 + rr;
        f32x4 o = *(const f32x4*)&Obuf[row][cc*4];
        __builtin_nontemporal_store(o,
            (f32x4*)&out[(((size_t)bh*LQ + a0 + row) << 6) + cc*4]);
    }
}

// ---------------------------------------------------------------------------
extern "C" void kernel_launch(void* const* d_in, const int* in_sizes, int n_in,
                              void* d_out, int out_size, void* d_ws, size_t ws_size,
                              hipStream_t stream) {
    const float* q   = (const float*)d_in[0];
    const float* WA  = (const float*)d_in[1];
    const float* WB  = (const float*)d_in[2];
    const float* WAt = (const float*)d_in[3];
    const float* WBt = (const float*)d_in[4];
    const float* Wav = (const float*)d_in[5];
    const float* Wbv = (const float*)d_in[6];
    const float* qt  = (const float*)d_in[7];
    const float* v   = (const float*)d_in[8];
    float* out = (float*)d_out;

    char* ws = (char*)d_ws;
    float*  W    = (float*)(ws);                          // 128 KB
    float*  Wv   = (float*)(ws + 131072);                 // 128 KB
    __bf16* qW   = (__bf16*)(ws + 262144);                // 8 MB
    __bf16* qtT  = (__bf16*)(ws + 262144 + 8388608);      // 8 MB
    __bf16* vWT  = (__bf16*)(ws + 262144 + 2*8388608);    // 8 MB
    float*  P1   = (float*)(ws + 262144);                 // 128 KB (aliases qW)
    float*  P2   = (float*)(ws + 262144 + 131072);        // 128 KB

    hipLaunchKernelGGL(fold_pairs, dim3(24), dim3(256), 0, stream,
                       WA, WB, WBt, WAt, Wav, Wbv, P1, P2, Wv);
    hipLaunchKernelGGL(fold_final, dim3(8),  dim3(256), 0, stream, P1, P2, W);
    hipLaunchKernelGGL(prepass,    dim3(64, 40), dim3(256), 0, stream,
                       q, W, qt, v, Wv, qW, qtT, vWT);

    // PROBE A x2: pure store path (garbage, overwritten below)
    hipLaunchKernelGGL(store_probe2, dim3(2048), dim3(256), 0, stream, out);
    // PROBE B x2: pure load/compute path
    hipLaunchKernelGGL(comp_probe2, dim3(2048), dim3(256), 0, stream,
                       qW, qtT, vWT, out);
    // Real kernel — produces the final correct output.
    hipLaunchKernelGGL(attn_kernel, dim3(2048), dim3(256), 0, stream,
                       qW, qtT, vWT, out);
}

// Round 9
// 184.527 us; speedup vs baseline: 3.6652x; 3.6652x over previous
//
#include <hip/hip_runtime.h>
#include <hip/hip_bf16.h>

// Problem constants
#define NB 8
#define NH 8
#define LQ 1024
#define LK 1024
#define DD 64
#define EC 0.18033688011112042f      // (1/8) * log2(e)
#define OUT0_SIZE (8ull*8*1024*64)   // output [B,H,LQ,D]

typedef __bf16 bf16x8 __attribute__((ext_vector_type(8)));
typedef __bf16 bf16x4 __attribute__((ext_vector_type(4)));
typedef float  f32x4  __attribute__((ext_vector_type(4)));

static __device__ __forceinline__ __bf16 f2b(float f) {
    unsigned u = __builtin_bit_cast(unsigned, f);
    unsigned r = (u + 0x7fffu + ((u >> 16) & 1u)) >> 16;
    return __builtin_bit_cast(__bf16, (unsigned short)r);
}

// ---------------------------------------------------------------------------
// K0a: independent 64x64x64 f32 products: P1=WA@WB, P2=WBt@WAt, Wv=Wav@Wbv
// ---------------------------------------------------------------------------
__global__ __launch_bounds__(256) void fold_pairs(
        const float* __restrict__ pWA, const float* __restrict__ pWB,
        const float* __restrict__ pWBt, const float* __restrict__ pWAt,
        const float* __restrict__ pWav, const float* __restrict__ pWbv,
        float* __restrict__ P1, float* __restrict__ P2, float* __restrict__ Wv) {
    __shared__ float AT[64*68];
    __shared__ float Bl[64*64];
    const int h = blockIdx.x / 3;
    const int which = blockIdx.x - h*3;
    const int t = threadIdx.x;
    const float *A, *B; float* C;
    if (which == 0)      { A = pWA  + h*4096; B = pWB  + h*4096; C = P1 + h*4096; }
    else if (which == 1) { A = pWBt + h*4096; B = pWAt + h*4096; C = P2 + h*4096; }
    else                 { A = pWav + h*4096; B = pWbv + h*4096; C = Wv + h*4096; }

    for (int i = t; i < 4096; i += 256) {
        int r = i >> 6, c = i & 63;
        AT[c*68 + r] = A[i];
        Bl[i] = B[i];
    }
    __syncthreads();
    const int r0 = (t >> 4) * 4, j0 = (t & 15) * 4;
    float acc[4][4] = {};
    #pragma unroll 8
    for (int k = 0; k < 64; ++k) {
        f32x4 a = *(const f32x4*)&AT[k*68 + r0];
        f32x4 b = *(const f32x4*)&Bl[k*64 + j0];
        #pragma unroll
        for (int i = 0; i < 4; ++i)
            #pragma unroll
            for (int j = 0; j < 4; ++j) acc[i][j] += a[i] * b[j];
    }
    #pragma unroll
    for (int i = 0; i < 4; ++i) {
        f32x4 o = { acc[i][0], acc[i][1], acc[i][2], acc[i][3] };
        *(f32x4*)&C[(r0 + i)*64 + j0] = o;
    }
}

// K0b: W = P1 @ P2
__global__ __launch_bounds__(256) void fold_final(
        const float* __restrict__ P1, const float* __restrict__ P2,
        float* __restrict__ Wout) {
    __shared__ float AT[64*68];
    __shared__ float Bl[64*64];
    const int h = blockIdx.x;
    const int t = threadIdx.x;
    for (int i = t; i < 4096; i += 256) {
        int r = i >> 6, c = i & 63;
        AT[c*68 + r] = P1[h*4096 + i];
        Bl[i] = P2[h*4096 + i];
    }
    __syncthreads();
    const int r0 = (t >> 4) * 4, j0 = (t & 15) * 4;
    float acc[4][4] = {};
    #pragma unroll 8
    for (int k = 0; k < 64; ++k) {
        f32x4 a = *(const f32x4*)&AT[k*68 + r0];
        f32x4 b = *(const f32x4*)&Bl[k*64 + j0];
        #pragma unroll
        for (int i = 0; i < 4; ++i)
            #pragma unroll
            for (int j = 0; j < 4; ++j) acc[i][j] += a[i] * b[j];
    }
    #pragma unroll
    for (int i = 0; i < 4; ++i) {
        f32x4 o = { acc[i][0], acc[i][1], acc[i][2], acc[i][3] };
        *(f32x4*)&Wout[h*4096 + (r0 + i)*64 + j0] = o;
    }
}

// ---------------------------------------------------------------------------
// K1 (merged prepass): blockIdx.y selects qW / qtT / vWT production
// ---------------------------------------------------------------------------
__global__ __launch_bounds__(256) void prepass(
        const float* __restrict__ q, const float* __restrict__ W,
        const float* __restrict__ qt, const float* __restrict__ v,
        const float* __restrict__ Wv,
        __bf16* __restrict__ qW, __bf16* __restrict__ qtT,
        __bf16* __restrict__ vWT) {
    __shared__ float smem[8448];
    const int bh = blockIdx.x;
    const int by = blockIdx.y;
    const int batch = bh >> 3, h = bh & 7;
    const int t = threadIdx.x;

    if (by < 16) {
        float* qT = smem;            // [c][r] 64x68
        float* Wl = smem + 4352;     // [c][j] 64x64
        const int a0 = by * 64;
        for (int i = t; i < 4096; i += 256) {
            int r = i >> 6, c = i & 63;
            Wl[i] = W[h*4096 + i];
            qT[c*68 + r] = q[(((size_t)batch*LQ + a0 + r)*NH + h)*DD + c];
        }
        __syncthreads();
        const int r0 = (t >> 4) * 4, j0 = (t & 15) * 4;
        float acc[4][4] = {};
        #pragma unroll 8
        for (int c = 0; c < 64; ++c) {
            f32x4 a = *(const f32x4*)&qT[c*68 + r0];
            f32x4 b = *(const f32x4*)&Wl[c*64 + j0];
            #pragma unroll
            for (int i = 0; i < 4; ++i)
                #pragma unroll
                for (int j = 0; j < 4; ++j) acc[i][j] += a[i] * b[j];
        }
        #pragma unroll
        for (int i = 0; i < 4; ++i) {
            bf16x4 o;
            #pragma unroll
            for (int j = 0; j < 4; ++j) o[j] = f2b(acc[i][j]);
            *(bf16x4*)&qW[((size_t)bh*LQ + a0 + r0 + i)*DD + j0] = o;
        }
    } else if (by < 24) {
        float* tile = smem;          // [j][n] 64x132
        const int n0 = (by - 16) * 128;
        #pragma unroll
        for (int it = 0; it < 8; ++it) {
            int idx = (t + 256*it) * 4;
            int j = idx >> 7, n = idx & 127;
            *(f32x4*)&tile[j*132 + n] = *(const f32x4*)&qt[((size_t)bh*DD + j)*LK + n0 + n];
        }
        __syncthreads();
        const int j0 = (t & 15) * 4;
        #pragma unroll
        for (int it = 0; it < 8; ++it) {
            int n = (t >> 4) + 16*it;
            bf16x4 o;
            #pragma unroll
            for (int i = 0; i < 4; ++i) o[i] = f2b(tile[(j0 + i)*132 + n]);
            *(bf16x4*)&qtT[((size_t)bh*LK + n0 + n)*DD + j0] = o;
        }
    } else {
        float* vT  = smem;           // [n][m] 64x68
        float* Wvl = smem + 4352;    // [n][c] 64x64
        const int mb0 = (by - 24) * 64;
        for (int i = t; i < 4096; i += 256) {
            int r = i >> 6, c = i & 63;     // r = m-row, c = n
            Wvl[i] = Wv[h*4096 + i];
            vT[c*68 + r] = v[(((size_t)batch*LK + mb0 + r)*NH + h)*DD + c];
        }
        __syncthreads();
        const int c0 = (t >> 4) * 4, m0 = (t & 15) * 4;
        float acc[4][4] = {};               // [c][m]
        #pragma unroll 8
        for (int n = 0; n < 64; ++n) {
            f32x4 wv = *(const f32x4*)&Wvl[n*64 + c0];
            f32x4 vv = *(const f32x4*)&vT[n*68 + m0];
            #pragma unroll
            for (int ci = 0; ci < 4; ++ci)
                #pragma unroll
                for (int mi = 0; mi < 4; ++mi) acc[ci][mi] += wv[ci] * vv[mi];
        }
        #pragma unroll
        for (int ci = 0; ci < 4; ++ci) {
            bf16x4 o;
            #pragma unroll
            for (int mi = 0; mi < 4; ++mi) o[mi] = f2b(acc[ci][mi]);
            *(bf16x4*)&vWT[((size_t)bh*DD + c0 + ci)*LK + mb0 + m0] = o;
        }
    }
}

// ---------------------------------------------------------------------------
// K4: ONE-PASS fused kernel. Compute S once; keep unnormalized p=exp2(S*EC)
// in registers (f32x4 p[8][4] = 128 VGPR); accumulate rsum AND unnormalized
// PV in the same loop (O is linear in P). After the cross-wave rsum reduce:
// oacc *= rinv, and a store-only loop emits p*rinv via the Pt contiguous
// NT-store schedule. Halves QK MFMAs, exp, and fragment loads vs R5.
// ---------------------------------------------------------------------------
__global__ __launch_bounds__(256) void attn_kernel(
        const __bf16* __restrict__ qW, const __bf16* __restrict__ qtT,
        const __bf16* __restrict__ vWT, float* __restrict__ out) {
    __shared__ __align__(16) __bf16 Elds[4][16][72];   // per-wave P tile (bf16, PV operand)
    __shared__ __align__(16) float  Pt[4][16][68];     // per-wave store staging
    __shared__ __align__(16) float  Obuf[32][68];      // block O tile
    __shared__ float rsumbuf[2][2][16];                // [nh][strip][q]

    const int bid = blockIdx.x;
    const int xcd = bid & 7, s = bid >> 3;
    const int bh  = xcd * 8 + (s >> 5);
    const int a0  = (s & 31) * 32;
    const int t   = threadIdx.x;
    const int w   = t >> 6, l = t & 63;
    const int lg  = l & 15, g = l >> 4;
    const int strip = w & 1, nh = w >> 1;
    const int qbase = a0 + strip * 16;
    const int n0w   = nh * 512;

    const __bf16* qtb = qtT + (size_t)bh * LK * DD;
    const __bf16* vwb = vWT + (size_t)bh * DD * LK;

    // B fragments (N = q)
    const bf16x8* qWp = reinterpret_cast<const bf16x8*>(qW + ((size_t)bh*LQ + qbase + lg)*DD);
    bf16x8 bfrag0 = qWp[g];
    bf16x8 bfrag1 = qWp[g + 4];

    // prefetch QK fragments for chunk 0
    bf16x8 ka[4][2];
    #pragma unroll
    for (int sub = 0; sub < 4; ++sub) {
        const bf16x8* qtp = (const bf16x8*)(qtb + (size_t)(n0w + sub*16 + lg)*DD);
        ka[sub][0] = qtp[g]; ka[sub][1] = qtp[g + 4];
    }

    f32x4 p[8][4];                 // unnormalized exp(S) (lane: 4 consecutive n per sub)
    float rsum = 0.f;
    f32x4 oacc[4];
    #pragma unroll
    for (int ct = 0; ct < 4; ++ct) oacc[ct] = f32x4{0.f, 0.f, 0.f, 0.f};

    #pragma unroll
    for (int nc = 0; nc < 8; ++nc) {
        const int nbase = n0w + nc*64;
        // vp loads for THIS chunk issued early (latency hidden under exp/MFMA below)
        bf16x8 vp0[4], vp1[4];
        #pragma unroll
        for (int ct = 0; ct < 4; ++ct) {
            const bf16x8* vpp = (const bf16x8*)(vwb + (size_t)(ct*16 + lg)*LK + nbase);
            vp0[ct] = vpp[g]; vp1[ct] = vpp[4 + g];
        }
        // QK MFMAs
        f32x4 accs[4];
        #pragma unroll
        for (int sub = 0; sub < 4; ++sub) {
            f32x4 acc = {0.f, 0.f, 0.f, 0.f};
            acc = __builtin_amdgcn_mfma_f32_16x16x32_bf16(ka[sub][0], bfrag0, acc, 0, 0, 0);
            acc = __builtin_amdgcn_mfma_f32_16x16x32_bf16(ka[sub][1], bfrag1, acc, 0, 0, 0);
            accs[sub] = acc;
        }
        // prefetch next chunk's QK fragments
        if (nc < 7) {
            #pragma unroll
            for (int sub = 0; sub < 4; ++sub) {
                const bf16x8* qtp = (const bf16x8*)(qtb + (size_t)(nbase + 64 + sub*16 + lg)*DD);
                ka[sub][0] = qtp[g]; ka[sub][1] = qtp[g + 4];
            }
        }
        // exp (unnormalized), keep in regs, bf16 to Elds, accumulate rsum
        #pragma unroll
        for (int sub = 0; sub < 4; ++sub) {
            bf16x4 pb;
            #pragma unroll
            for (int r = 0; r < 4; ++r) {
                float pv_ = __builtin_exp2f(accs[sub][r] * EC);
                p[nc][sub][r] = pv_;
                pb[r] = f2b(pv_);
                rsum += pv_;
            }
            *(bf16x4*)&Elds[w][lg][sub*16 + g*4] = pb;
        }
        // PV MFMAs (unnormalized accumulation)
        bf16x8 pf0 = ((const bf16x8*)&Elds[w][lg][0])[g];
        bf16x8 pf1 = ((const bf16x8*)&Elds[w][lg][0])[4 + g];
        #pragma unroll
        for (int ct = 0; ct < 4; ++ct) {
            oacc[ct] = __builtin_amdgcn_mfma_f32_16x16x32_bf16(vp0[ct], pf0, oacc[ct], 0, 0, 0);
            oacc[ct] = __builtin_amdgcn_mfma_f32_16x16x32_bf16(vp1[ct], pf1, oacc[ct], 0, 0, 0);
        }
    }

    // ---- cross-wave rsum reduce ----
    rsum += __shfl_xor(rsum, 16);
    rsum += __shfl_xor(rsum, 32);
    if (l < 16) rsumbuf[nh][strip][l] = rsum;
    __syncthreads();
    const float rinv = 1.0f / (rsumbuf[0][strip][lg] + rsumbuf[1][strip][lg]);

    // ---- O: scale by rinv, cross-wave reduce, contiguous NT store ----
    #pragma unroll
    for (int ct = 0; ct < 4; ++ct) oacc[ct] *= rinv;

    const int rr = l >> 4, cc = l & 15;
    if (nh == 1) {
        #pragma unroll
        for (int ct = 0; ct < 4; ++ct)
            *(f32x4*)&Obuf[strip*16 + lg][ct*16 + g*4] = oacc[ct];
    }
    __syncthreads();
    if (nh == 0) {
        #pragma unroll
        for (int ct = 0; ct < 4; ++ct) {
            f32x4 o = *(const f32x4*)&Obuf[strip*16 + lg][ct*16 + g*4];
            o = o + oacc[ct];
            *(f32x4*)&Obuf[strip*16 + lg][ct*16 + g*4] = o;
        }
    }
    __syncthreads();
    #pragma unroll
    for (int it = 0; it < 2; ++it) {
        int row = it*16 + w*4 + rr;           // 0..31
        f32x4 o = *(const f32x4*)&Obuf[row][cc*4];
        __builtin_nontemporal_store(o,
            (f32x4*)&out[(((size_t)bh*LQ + a0 + row) << 6) + cc*4]);
    }

    // ---- attn: store-only loop (p * rinv), Pt-staged contiguous NT stores ----
    float* attnb = out + OUT0_SIZE + ((size_t)bh << 20);
    #pragma unroll
    for (int nc = 0; nc < 8; ++nc) {
        const int nbase = n0w + nc*64;
        #pragma unroll
        for (int sub = 0; sub < 4; ++sub) {
            f32x4 ps = p[nc][sub] * rinv;
            *(f32x4*)&Pt[w][lg][sub*16 + g*4] = ps;
        }
        #pragma unroll
        for (int it = 0; it < 4; ++it) {
            int row = it*4 + rr;
            f32x4 pp = *(const f32x4*)&Pt[w][row][cc*4];
            __builtin_nontemporal_store(pp,
                (f32x4*)&attnb[((size_t)(qbase + row) << 10) + nbase + cc*4]);
        }
    }
}

// ---------------------------------------------------------------------------
extern "C" void kernel_launch(void* const* d_in, const int* in_sizes, int n_in,
                              void* d_out, int out_size, void* d_ws, size_t ws_size,
                              hipStream_t stream) {
    const float* q   = (const float*)d_in[0];
    const float* WA  = (const float*)d_in[1];
    const float* WB  = (const float*)d_in[2];
    const float* WAt = (const float*)d_in[3];
    const float* WBt = (const float*)d_in[4];
    const float* Wav = (const float*)d_in[5];
    const float* Wbv = (const float*)d_in[6];
    const float* qt  = (const float*)d_in[7];
    const float* v   = (const float*)d_in[8];
    float* out = (float*)d_out;

    char* ws = (char*)d_ws;
    float*  W    = (float*)(ws);                          // 128 KB
    float*  Wv   = (float*)(ws + 131072);                 // 128 KB
    __bf16* qW   = (__bf16*)(ws + 262144);                // 8 MB
    __bf16* qtT  = (__bf16*)(ws + 262144 + 8388608);      // 8 MB
    __bf16* vWT  = (__bf16*)(ws + 262144 + 2*8388608);    // 8 MB
    float*  P1   = (float*)(ws + 262144);                 // 128 KB (aliases qW)
    float*  P2   = (float*)(ws + 262144 + 131072);        // 128 KB

    hipLaunchKernelGGL(fold_pairs, dim3(24), dim3(256), 0, stream,
                       WA, WB, WBt, WAt, Wav, Wbv, P1, P2, Wv);
    hipLaunchKernelGGL(fold_final, dim3(8),  dim3(256), 0, stream, P1, P2, W);
    hipLaunchKernelGGL(prepass,    dim3(64, 40), dim3(256), 0, stream,
                       q, W, qt, v, Wv, qW, qtT, vWT);
    hipLaunchKernelGGL(attn_kernel, dim3(2048), dim3(256), 0, stream,
                       qW, qtT, vWT, out);
}

// Round 10
// 151.457 us; speedup vs baseline: 4.4654x; 1.2183x over previous
//
#include <hip/hip_runtime.h>
#include <hip/hip_bf16.h>

// Problem constants
#define NB 8
#define NH 8
#define LQ 1024
#define LK 1024
#define DD 64
#define EC 0.18033688011112042f      // (1/8) * log2(e)
#define OUT0_SIZE (8ull*8*1024*64)   // output [B,H,LQ,D]

typedef __bf16 bf16x8 __attribute__((ext_vector_type(8)));
typedef __bf16 bf16x4 __attribute__((ext_vector_type(4)));
typedef float  f32x4  __attribute__((ext_vector_type(4)));
typedef unsigned int u32x4 __attribute__((ext_vector_type(4)));
typedef unsigned int u32x2 __attribute__((ext_vector_type(2)));

static __device__ __forceinline__ __bf16 f2b(float f) {
    unsigned u = __builtin_bit_cast(unsigned, f);
    unsigned r = (u + 0x7fffu + ((u >> 16) & 1u)) >> 16;
    return __builtin_bit_cast(__bf16, (unsigned short)r);
}
static __device__ __forceinline__ unsigned bpack(float a, float b) {
    return (unsigned)__builtin_bit_cast(unsigned short, f2b(a))
         | ((unsigned)__builtin_bit_cast(unsigned short, f2b(b)) << 16);
}

// ---------------------------------------------------------------------------
// K0a: independent 64x64x64 f32 products: P1=WA@WB, P2=WBt@WAt, Wv=Wav@Wbv
// ---------------------------------------------------------------------------
__global__ __launch_bounds__(256) void fold_pairs(
        const float* __restrict__ pWA, const float* __restrict__ pWB,
        const float* __restrict__ pWBt, const float* __restrict__ pWAt,
        const float* __restrict__ pWav, const float* __restrict__ pWbv,
        float* __restrict__ P1, float* __restrict__ P2, float* __restrict__ Wv) {
    __shared__ float AT[64*68];
    __shared__ float Bl[64*64];
    const int h = blockIdx.x / 3;
    const int which = blockIdx.x - h*3;
    const int t = threadIdx.x;
    const float *A, *B; float* C;
    if (which == 0)      { A = pWA  + h*4096; B = pWB  + h*4096; C = P1 + h*4096; }
    else if (which == 1) { A = pWBt + h*4096; B = pWAt + h*4096; C = P2 + h*4096; }
    else                 { A = pWav + h*4096; B = pWbv + h*4096; C = Wv + h*4096; }

    for (int i = t; i < 4096; i += 256) {
        int r = i >> 6, c = i & 63;
        AT[c*68 + r] = A[i];
        Bl[i] = B[i];
    }
    __syncthreads();
    const int r0 = (t >> 4) * 4, j0 = (t & 15) * 4;
    float acc[4][4] = {};
    #pragma unroll 8
    for (int k = 0; k < 64; ++k) {
        f32x4 a = *(const f32x4*)&AT[k*68 + r0];
        f32x4 b = *(const f32x4*)&Bl[k*64 + j0];
        #pragma unroll
        for (int i = 0; i < 4; ++i)
            #pragma unroll
            for (int j = 0; j < 4; ++j) acc[i][j] += a[i] * b[j];
    }
    #pragma unroll
    for (int i = 0; i < 4; ++i) {
        f32x4 o = { acc[i][0], acc[i][1], acc[i][2], acc[i][3] };
        *(f32x4*)&C[(r0 + i)*64 + j0] = o;
    }
}

// K0b: W = P1 @ P2
__global__ __launch_bounds__(256) void fold_final(
        const float* __restrict__ P1, const float* __restrict__ P2,
        float* __restrict__ Wout) {
    __shared__ float AT[64*68];
    __shared__ float Bl[64*64];
    const int h = blockIdx.x;
    const int t = threadIdx.x;
    for (int i = t; i < 4096; i += 256) {
        int r = i >> 6, c = i & 63;
        AT[c*68 + r] = P1[h*4096 + i];
        Bl[i] = P2[h*4096 + i];
    }
    __syncthreads();
    const int r0 = (t >> 4) * 4, j0 = (t & 15) * 4;
    float acc[4][4] = {};
    #pragma unroll 8
    for (int k = 0; k < 64; ++k) {
        f32x4 a = *(const f32x4*)&AT[k*68 + r0];
        f32x4 b = *(const f32x4*)&Bl[k*64 + j0];
        #pragma unroll
        for (int i = 0; i < 4; ++i)
            #pragma unroll
            for (int j = 0; j < 4; ++j) acc[i][j] += a[i] * b[j];
    }
    #pragma unroll
    for (int i = 0; i < 4; ++i) {
        f32x4 o = { acc[i][0], acc[i][1], acc[i][2], acc[i][3] };
        *(f32x4*)&Wout[h*4096 + (r0 + i)*64 + j0] = o;
    }
}

// ---------------------------------------------------------------------------
// K1 (merged prepass): blockIdx.y selects qW / qtT / vWT production.
// vWT is now TILED: [bh][mchunk(16)][c(64)][mlocal(64)] so attn V-staging
// loads are fully contiguous 1KB per instruction.
// ---------------------------------------------------------------------------
__global__ __launch_bounds__(256) void prepass(
        const float* __restrict__ q, const float* __restrict__ W,
        const float* __restrict__ qt, const float* __restrict__ v,
        const float* __restrict__ Wv,
        __bf16* __restrict__ qW, __bf16* __restrict__ qtT,
        __bf16* __restrict__ vWT) {
    __shared__ float smem[8448];
    const int bh = blockIdx.x;
    const int by = blockIdx.y;
    const int batch = bh >> 3, h = bh & 7;
    const int t = threadIdx.x;

    if (by < 16) {
        float* qT = smem;            // [c][r] 64x68
        float* Wl = smem + 4352;     // [c][j] 64x64
        const int a0 = by * 64;
        for (int i = t; i < 4096; i += 256) {
            int r = i >> 6, c = i & 63;
            Wl[i] = W[h*4096 + i];
            qT[c*68 + r] = q[(((size_t)batch*LQ + a0 + r)*NH + h)*DD + c];
        }
        __syncthreads();
        const int r0 = (t >> 4) * 4, j0 = (t & 15) * 4;
        float acc[4][4] = {};
        #pragma unroll 8
        for (int c = 0; c < 64; ++c) {
            f32x4 a = *(const f32x4*)&qT[c*68 + r0];
            f32x4 b = *(const f32x4*)&Wl[c*64 + j0];
            #pragma unroll
            for (int i = 0; i < 4; ++i)
                #pragma unroll
                for (int j = 0; j < 4; ++j) acc[i][j] += a[i] * b[j];
        }
        #pragma unroll
        for (int i = 0; i < 4; ++i) {
            bf16x4 o;
            #pragma unroll
            for (int j = 0; j < 4; ++j) o[j] = f2b(acc[i][j]);
            *(bf16x4*)&qW[((size_t)bh*LQ + a0 + r0 + i)*DD + j0] = o;
        }
    } else if (by < 24) {
        float* tile = smem;          // [j][n] 64x132
        const int n0 = (by - 16) * 128;
        #pragma unroll
        for (int it = 0; it < 8; ++it) {
            int idx = (t + 256*it) * 4;
            int j = idx >> 7, n = idx & 127;
            *(f32x4*)&tile[j*132 + n] = *(const f32x4*)&qt[((size_t)bh*DD + j)*LK + n0 + n];
        }
        __syncthreads();
        const int j0 = (t & 15) * 4;
        #pragma unroll
        for (int it = 0; it < 8; ++it) {
            int n = (t >> 4) + 16*it;
            bf16x4 o;
            #pragma unroll
            for (int i = 0; i < 4; ++i) o[i] = f2b(tile[(j0 + i)*132 + n]);
            *(bf16x4*)&qtT[((size_t)bh*LK + n0 + n)*DD + j0] = o;
        }
    } else {
        float* vT  = smem;           // [n][m] 64x68
        float* Wvl = smem + 4352;    // [n][c] 64x64
        const int mb0 = (by - 24) * 64;
        const int mb  = by - 24;     // m-chunk index 0..15
        for (int i = t; i < 4096; i += 256) {
            int r = i >> 6, c = i & 63;     // r = m-row, c = n
            Wvl[i] = Wv[h*4096 + i];
            vT[c*68 + r] = v[(((size_t)batch*LK + mb0 + r)*NH + h)*DD + c];
        }
        __syncthreads();
        const int c0 = (t >> 4) * 4, m0 = (t & 15) * 4;
        float acc[4][4] = {};               // [c][m]
        #pragma unroll 8
        for (int n = 0; n < 64; ++n) {
            f32x4 wv = *(const f32x4*)&Wvl[n*64 + c0];
            f32x4 vv = *(const f32x4*)&vT[n*68 + m0];
            #pragma unroll
            for (int ci = 0; ci < 4; ++ci)
                #pragma unroll
                for (int mi = 0; mi < 4; ++mi) acc[ci][mi] += wv[ci] * vv[mi];
        }
        // tiled layout: [bh][mb][c][mlocal]
        #pragma unroll
        for (int ci = 0; ci < 4; ++ci) {
            bf16x4 o;
            #pragma unroll
            for (int mi = 0; mi < 4; ++mi) o[mi] = f2b(acc[ci][mi]);
            *(bf16x4*)&vWT[((((size_t)bh*16 + mb)*64) + c0 + ci)*64 + m0] = o;
        }
    }
}

// ---------------------------------------------------------------------------
// K4: one-pass fused attn with LDS-staged K/V tiles.
// Per 64-key chunk: 4 waves cooperatively stage K(8KB)+V(8KB) per n-half
// with fully-contiguous 1KB loads (reg->LDS, padded rows), then read MFMA
// fragments from LDS. Eliminates strip-duplicated scattered fragment loads
// (global segments per block-chunk: 1024 -> 256). p kept packed bf16 in
// 64 VGPRs; deferred normalization as in R9.
// ---------------------------------------------------------------------------
__global__ __launch_bounds__(256) void attn_kernel(
        const __bf16* __restrict__ qW, const __bf16* __restrict__ qtT,
        const __bf16* __restrict__ vWT, float* __restrict__ out) {
    __shared__ __align__(16) __bf16 Kbuf[2][64][80];   // 20.0 KB
    __shared__ __align__(16) __bf16 Vbuf[2][64][80];   // 20.0 KB
    __shared__ __align__(16) __bf16 Elds[4][16][80];   // 10.0 KB
    __shared__ __align__(16) float  Pt[4][16][72];     // 18.0 KB
    __shared__ __align__(16) float  Obuf[32][72];      //  9.0 KB
    __shared__ float rsumbuf[2][2][16];

    const int bid = blockIdx.x;
    const int xcd = bid & 7, s = bid >> 3;
    const int bh  = xcd * 8 + (s >> 5);
    const int a0  = (s & 31) * 32;
    const int t   = threadIdx.x;
    const int w   = t >> 6, l = t & 63;
    const int lg  = l & 15, g = l >> 4;
    const int strip = w & 1, nh = w >> 1;
    const int qbase = a0 + strip * 16;
    const int n0w   = nh * 512;
    const int srow = l >> 3, scol = l & 7;   // staging lane mapping

    const __bf16* qtb = qtT + (size_t)bh * LK * DD;
    const __bf16* vwb = vWT + (size_t)bh * LK * DD;   // tiled [16][64][64]

    // B fragments (N = q)
    const bf16x8* qWp = reinterpret_cast<const bf16x8*>(qW + ((size_t)bh*LQ + qbase + lg)*DD);
    bf16x8 bfrag0 = qWp[g];
    bf16x8 bfrag1 = qWp[g + 4];

    // staging sources for this wave: (w&1)==0 -> K tile of nh; else V tile of nh
    const __bf16* gK = qtb + (size_t)(nh*512)*64;
    const __bf16* gV = vwb;  // chunk base computed per nc: (nh*8+nc)*4096
    u32x4 stg[8];

#define LOADSTG(NC)                                                            \
    if ((w & 1) == 0) {                                                        \
        _Pragma("unroll")                                                      \
        for (int i = 0; i < 8; ++i)                                            \
            stg[i] = *(const u32x4*)(gK + ((size_t)((NC)*64 + 8*i + srow))*64 + scol*8); \
    } else {                                                                   \
        const __bf16* vb = gV + (size_t)(nh*8 + (NC))*4096;                    \
        _Pragma("unroll")                                                      \
        for (int i = 0; i < 8; ++i)                                            \
            stg[i] = *(const u32x4*)(vb + (size_t)(8*i + srow)*64 + scol*8);   \
    }

#define WRITESTG()                                                             \
    {                                                                          \
        __bf16* dst = (w & 1) == 0 ? &Kbuf[nh][0][0] : &Vbuf[nh][0][0];        \
        _Pragma("unroll")                                                      \
        for (int i = 0; i < 8; ++i)                                            \
            *(u32x4*)&dst[(8*i + srow)*80 + scol*8] = stg[i];                  \
    }

    // prologue: stage chunk 0
    LOADSTG(0);
    WRITESTG();
    __syncthreads();

    u32x2 ppk[8][4];               // packed unnormalized exp(S), bf16 x4 per entry
    float rsum = 0.f;
    f32x4 oacc[4];
    #pragma unroll
    for (int ct = 0; ct < 4; ++ct) oacc[ct] = f32x4{0.f, 0.f, 0.f, 0.f};

    #pragma unroll
    for (int nc = 0; nc < 8; ++nc) {
        // ---- QK from LDS ----
        f32x4 accs[4];
        #pragma unroll
        for (int sub = 0; sub < 4; ++sub) {
            const __bf16* kr = &Kbuf[nh][sub*16 + lg][0];
            bf16x8 a0 = *(const bf16x8*)&kr[g*8];
            bf16x8 a1 = *(const bf16x8*)&kr[g*8 + 32];
            f32x4 acc = {0.f, 0.f, 0.f, 0.f};
            acc = __builtin_amdgcn_mfma_f32_16x16x32_bf16(a0, bfrag0, acc, 0, 0, 0);
            acc = __builtin_amdgcn_mfma_f32_16x16x32_bf16(a1, bfrag1, acc, 0, 0, 0);
            accs[sub] = acc;
        }
        // issue next chunk's staging loads early (hide HBM/L2 latency)
        if (nc < 7) { LOADSTG(nc + 1); }
        // ---- exp, pack, rsum, Elds ----
        #pragma unroll
        for (int sub = 0; sub < 4; ++sub) {
            float p0 = __builtin_exp2f(accs[sub][0] * EC);
            float p1 = __builtin_exp2f(accs[sub][1] * EC);
            float p2 = __builtin_exp2f(accs[sub][2] * EC);
            float p3 = __builtin_exp2f(accs[sub][3] * EC);
            rsum += (p0 + p1) + (p2 + p3);
            u32x2 pk;
            pk.x = bpack(p0, p1);
            pk.y = bpack(p2, p3);
            ppk[nc][sub] = pk;
            *(u32x2*)&Elds[w][lg][sub*16 + g*4] = pk;
        }
        // ---- PV from LDS ----
        const __bf16* er = &Elds[w][lg][0];
        bf16x8 pf0 = *(const bf16x8*)&er[g*8];
        bf16x8 pf1 = *(const bf16x8*)&er[g*8 + 32];
        #pragma unroll
        for (int ct = 0; ct < 4; ++ct) {
            const __bf16* vr = &Vbuf[nh][ct*16 + lg][0];
            bf16x8 v0 = *(const bf16x8*)&vr[g*8];
            bf16x8 v1 = *(const bf16x8*)&vr[g*8 + 32];
            oacc[ct] = __builtin_amdgcn_mfma_f32_16x16x32_bf16(v0, pf0, oacc[ct], 0, 0, 0);
            oacc[ct] = __builtin_amdgcn_mfma_f32_16x16x32_bf16(v1, pf1, oacc[ct], 0, 0, 0);
        }
        // ---- buffer swap: all waves done reading, then write next tiles ----
        __syncthreads();
        if (nc < 7) { WRITESTG(); }
        __syncthreads();
    }

    // ---- cross-wave rsum reduce ----
    rsum += __shfl_xor(rsum, 16);
    rsum += __shfl_xor(rsum, 32);
    if (l < 16) rsumbuf[nh][strip][l] = rsum;
    __syncthreads();
    const float rinv = 1.0f / (rsumbuf[0][strip][lg] + rsumbuf[1][strip][lg]);

    // ---- O: scale, cross-wave reduce, contiguous NT store ----
    #pragma unroll
    for (int ct = 0; ct < 4; ++ct) oacc[ct] *= rinv;

    const int rr = l >> 4, cc = l & 15;
    if (nh == 1) {
        #pragma unroll
        for (int ct = 0; ct < 4; ++ct)
            *(f32x4*)&Obuf[strip*16 + lg][ct*16 + g*4] = oacc[ct];
    }
    __syncthreads();
    if (nh == 0) {
        #pragma unroll
        for (int ct = 0; ct < 4; ++ct) {
            f32x4 o = *(const f32x4*)&Obuf[strip*16 + lg][ct*16 + g*4];
            o = o + oacc[ct];
            *(f32x4*)&Obuf[strip*16 + lg][ct*16 + g*4] = o;
        }
    }
    __syncthreads();
    #pragma unroll
    for (int it = 0; it < 2; ++it) {
        int row = it*16 + w*4 + rr;           // 0..31
        f32x4 o = *(const f32x4*)&Obuf[row][cc*4];
        __builtin_nontemporal_store(o,
            (f32x4*)&out[(((size_t)bh*LQ + a0 + row) << 6) + cc*4]);
    }

    // ---- attn store phase: unpack ppk, *rinv, Pt-staged contiguous NT ----
    float* attnb = out + OUT0_SIZE + ((size_t)bh << 20);
    #pragma unroll
    for (int nc = 0; nc < 8; ++nc) {
        const int nbase = n0w + nc*64;
        #pragma unroll
        for (int sub = 0; sub < 4; ++sub) {
            unsigned lo = ppk[nc][sub].x, hi = ppk[nc][sub].y;
            f32x4 ps;
            ps[0] = __builtin_bit_cast(float, lo << 16) * rinv;
            ps[1] = __builtin_bit_cast(float, lo & 0xffff0000u) * rinv;
            ps[2] = __builtin_bit_cast(float, hi << 16) * rinv;
            ps[3] = __builtin_bit_cast(float, hi & 0xffff0000u) * rinv;
            *(f32x4*)&Pt[w][lg][sub*16 + g*4] = ps;
        }
        #pragma unroll
        for (int it = 0; it < 4; ++it) {
            int row = it*4 + rr;
            f32x4 pp = *(const f32x4*)&Pt[w][row][cc*4];
            __builtin_nontemporal_store(pp,
                (f32x4*)&attnb[((size_t)(qbase + row) << 10) + nbase + cc*4]);
        }
    }
#undef LOADSTG
#undef WRITESTG
}

// ---------------------------------------------------------------------------
extern "C" void kernel_launch(void* const* d_in, const int* in_sizes, int n_in,
                              void* d_out, int out_size, void* d_ws, size_t ws_size,
                              hipStream_t stream) {
    const float* q   = (const float*)d_in[0];
    const float* WA  = (const float*)d_in[1];
    const float* WB  = (const float*)d_in[2];
    const float* WAt = (const float*)d_in[3];
    const float* WBt = (const float*)d_in[4];
    const float* Wav = (const float*)d_in[5];
    const float* Wbv = (const float*)d_in[6];
    const float* qt  = (const float*)d_in[7];
    const float* v   = (const float*)d_in[8];
    float* out = (float*)d_out;

    char* ws = (char*)d_ws;
    float*  W    = (float*)(ws);                          // 128 KB
    float*  Wv   = (float*)(ws + 131072);                 // 128 KB
    __bf16* qW   = (__bf16*)(ws + 262144);                // 8 MB
    __bf16* qtT  = (__bf16*)(ws + 262144 + 8388608);      // 8 MB
    __bf16* vWT  = (__bf16*)(ws + 262144 + 2*8388608);    // 8 MB (tiled)
    float*  P1   = (float*)(ws + 262144);                 // 128 KB (aliases qW)
    float*  P2   = (float*)(ws + 262144 + 131072);        // 128 KB

    hipLaunchKernelGGL(fold_pairs, dim3(24), dim3(256), 0, stream,
                       WA, WB, WBt, WAt, Wav, Wbv, P1, P2, Wv);
    hipLaunchKernelGGL(fold_final, dim3(8),  dim3(256), 0, stream, P1, P2, W);
    hipLaunchKernelGGL(prepass,    dim3(64, 40), dim3(256), 0, stream,
                       q, W, qt, v, Wv, qW, qtT, vWT);
    hipLaunchKernelGGL(attn_kernel, dim3(2048), dim3(256), 0, stream,
                       qW, qtT, vWT, out);
}